// Round 4
// baseline (1777.714 us; speedup 1.0000x reference)
//
#include <hip/hip_runtime.h>

// ---------------------------------------------------------------------------
// DendriticMLP on MI355X — round 4.
// f16 hi/lo split GEMMs (3-term MFMA hh+hl+lh, ~2^-21 error) as round 3, plus:
//  - double-buffered LDS K-loop, ONE barrier per K-step, all global/DMA issue
//    BEFORE the MFMA phase so the barrier's vmcnt(0) drain is covered by MFMA
//    (round-3 issued the B prefetch right before the barrier => full-latency
//    stall every step).
//  - LDS 73728/65536 B: free, since VGPR+AGPR (~176) already caps 2 blocks/CU.
// Workspace: 96 MB, time-multiplexed as round 3.
// ---------------------------------------------------------------------------

#define AS1 __attribute__((address_space(1)))
#define AS3 __attribute__((address_space(3)))

typedef _Float16 f16x8 __attribute__((ext_vector_type(8)));
typedef _Float16 f16x4 __attribute__((ext_vector_type(4)));
typedef float    f32x4 __attribute__((ext_vector_type(4)));

// swizzled halfword offset of logical chunk q (0..3) in row of a [rows][32]
// f16 tile: physical chunk = q ^ ((row>>1)&3) -> frag reads 2-way max (free).
__device__ __forceinline__ int swz(int row, int q) {
    return row * 32 + ((q ^ ((row >> 1) & 3)) << 3);
}

// ---------------------------------------------------------------------------
// split: fp32 -> f16 hi + f16 lo planes (a ~= hi+lo, err ~2^-22 |a|)
// ---------------------------------------------------------------------------
__global__ __launch_bounds__(256) void split_kernel(const float* __restrict__ s,
                                                    _Float16* __restrict__ hi,
                                                    _Float16* __restrict__ lo, int n4) {
    int i = blockIdx.x * 256 + threadIdx.x;
    if (i >= n4) return;
    float4 a = ((const float4*)s)[i];
    f16x4 h, l;
    h.x = (_Float16)a.x; l.x = (_Float16)(a.x - (float)h.x);
    h.y = (_Float16)a.y; l.y = (_Float16)(a.y - (float)h.y);
    h.z = (_Float16)a.z; l.z = (_Float16)(a.z - (float)h.z);
    h.w = (_Float16)a.w; l.w = (_Float16)(a.w - (float)h.w);
    ((f16x4*)hi)[i] = h;
    ((f16x4*)lo)[i] = l;
}

// DMA one 128x32 f16 plane tile into swizzled LDS (wave-uniform base+lane*16).
__device__ __forceinline__ void dma_plane(const _Float16* __restrict__ g, long row0,
                                          int ldHalf, int kcol, _Float16* lds, int tid) {
#pragma unroll
    for (int rep = 0; rep < 2; ++rep) {
        const int s = tid + rep * 256;           // physical 16B slot, 512 total
        const int row = s >> 2, cp = s & 3;
        const int src = cp ^ ((row >> 1) & 3);   // logical chunk at this slot
        const _Float16* gp = g + (row0 + row) * (long)ldHalf + kcol + src * 8;
        __builtin_amdgcn_global_load_lds((const AS1 void*)gp,
                                         (AS3 void*)(lds + ((s & ~63) << 3)), 16, 0, 0);
    }
}

// convert a prefetched float4 to hi/lo f16x4 and store to swizzled LDS planes
__device__ __forceinline__ void cvt_store(const float4 v, int c, _Float16* sH,
                                          _Float16* sL) {
    const int row = c >> 3, hc = c & 7;
    f16x4 h, l;
    h.x = (_Float16)v.x; l.x = (_Float16)(v.x - (float)h.x);
    h.y = (_Float16)v.y; l.y = (_Float16)(v.y - (float)h.y);
    h.z = (_Float16)v.z; l.z = (_Float16)(v.z - (float)h.z);
    h.w = (_Float16)v.w; l.w = (_Float16)(v.w - (float)h.w);
    const int off = row * 32 + (((hc >> 1) ^ ((row >> 1) & 3)) << 3) + ((hc & 1) << 2);
    *(f16x4*)(sH + off) = h;
    *(f16x4*)(sL + off) = l;
}

// ---------------------------------------------------------------------------
// Split GEMM: C[M,N] = A[M,K] @ B[N,K]^T + bias[N]; A = f16 hi/lo planes (DMA),
// B fp32 (global prefetch + in-register split). 128x128 tile, 4 waves 2x2,
// 4x4 of 16x16x32_f16, 3 MFMAs/pair. Double-buffered, 1 barrier/K-step.
// ---------------------------------------------------------------------------
__global__ __launch_bounds__(256) void gemm_split(
    const _Float16* __restrict__ AH, const _Float16* __restrict__ AL,
    const float* __restrict__ B, const float* __restrict__ bias,
    float* __restrict__ C, int N, int K) {
    __shared__ __align__(16) _Float16 sAh[2][4096], sAl[2][4096];
    __shared__ __align__(16) _Float16 sBh[2][4096], sBl[2][4096];
    const int tid = threadIdx.x;
    const int w = tid >> 6, lane = tid & 63;
    const int wm = w >> 1, wn = w & 1;
    const int q = lane >> 4, l15 = lane & 15;
    const int bm = blockIdx.y, bn = blockIdx.x;
    const long brow0 = (long)bn * 128;
    f32x4 acc[4][4] = {};
    float4 pre[4];
    auto loadB = [&](int kt) {
#pragma unroll
        for (int j = 0; j < 4; ++j) {
            const int c = tid + j * 256;
            pre[j] = *(const float4*)(B + (brow0 + (c >> 3)) * (long)K + (kt << 5) +
                                      ((c & 7) << 2));
        }
    };
    auto writeB = [&](int buf) {
#pragma unroll
        for (int j = 0; j < 4; ++j) cvt_store(pre[j], tid + j * 256, sBh[buf], sBl[buf]);
    };
    const int ksteps = K >> 5;
    loadB(0);
    dma_plane(AH, (long)bm * 128, K, 0, sAh[0], tid);
    dma_plane(AL, (long)bm * 128, K, 0, sAl[0], tid);
    writeB(0);
    loadB(1);
    __syncthreads();
    for (int kt = 0; kt < ksteps; ++kt) {
        const int cur = kt & 1, nxt = cur ^ 1;
        if (kt + 1 < ksteps) {
            const int kcol = (kt + 1) << 5;
            dma_plane(AH, (long)bm * 128, K, kcol, sAh[nxt], tid);
            dma_plane(AL, (long)bm * 128, K, kcol, sAl[nxt], tid);
            writeB(nxt);                      // consumes pre = B(kt+1)
            if (kt + 2 < ksteps) loadB(kt + 2);
        }
        f16x8 aH[4], aL[4];
#pragma unroll
        for (int tm = 0; tm < 4; ++tm) {
            const int row = wm * 64 + tm * 16 + l15;
            aH[tm] = *(const f16x8*)&sAh[cur][swz(row, q)];
            aL[tm] = *(const f16x8*)&sAl[cur][swz(row, q)];
        }
#pragma unroll
        for (int tn = 0; tn < 4; ++tn) {
            const int rowb = wn * 64 + tn * 16 + l15;
            const f16x8 bH = *(const f16x8*)&sBh[cur][swz(rowb, q)];
            const f16x8 bL = *(const f16x8*)&sBl[cur][swz(rowb, q)];
#pragma unroll
            for (int tm = 0; tm < 4; ++tm) {
                acc[tm][tn] = __builtin_amdgcn_mfma_f32_16x16x32_f16(aH[tm], bH, acc[tm][tn], 0, 0, 0);
                acc[tm][tn] = __builtin_amdgcn_mfma_f32_16x16x32_f16(aH[tm], bL, acc[tm][tn], 0, 0, 0);
                acc[tm][tn] = __builtin_amdgcn_mfma_f32_16x16x32_f16(aL[tm], bH, acc[tm][tn], 0, 0, 0);
            }
        }
        __syncthreads();  // drains kt+1 DMA/writes; all reads of cur done
    }
    float bv[4];
#pragma unroll
    for (int tn = 0; tn < 4; ++tn) bv[tn] = bias[bn * 128 + wn * 64 + tn * 16 + l15];
#pragma unroll
    for (int tm = 0; tm < 4; ++tm) {
        const int m0 = bm * 128 + wm * 64 + tm * 16 + q * 4;
#pragma unroll
        for (int tn = 0; tn < 4; ++tn) {
            const int n = bn * 128 + wn * 64 + tn * 16 + l15;
#pragma unroll
            for (int r = 0; r < 4; ++r)
                C[(long)(m0 + r) * N + n] = acc[tm][tn][r] + bv[tn];
        }
    }
}

// ---------------------------------------------------------------------------
// Dendrite GEMM + abs-max gating epilogue (one layer per launch).
// dend[b,n] = ctx[b,:].seg[n,:], n = h*10+s. Tile 128(b)x160(n). ctx planes
// via DMA, seg fp32 prefetch+split. Double-buffered, 1 barrier/K-step.
// Epilogue: acc -> LDS [64][160], argmax_s |dend| (strict > = jnp.argmax),
// gates[b][h] = sigmoid(selected).
// ---------------------------------------------------------------------------
__global__ __launch_bounds__(256) void dend_gemm(const _Float16* __restrict__ AH,
                                                 const _Float16* __restrict__ AL,
                                                 const float* __restrict__ seg,
                                                 float* __restrict__ gates) {
    __shared__ __align__(16) char smem[73728];  // 2 x 36864
    const int tid = threadIdx.x;
    const int w = tid >> 6, lane = tid & 63;
    const int wm = w >> 1, wn = w & 1;
    const int q = lane >> 4, l15 = lane & 15;
    const int bm = blockIdx.y, bn = blockIdx.x;
    const long brow0 = (long)bn * 160;
    _Float16* sAh[2];
    _Float16* sAl[2];
    _Float16* sBh[2];
    _Float16* sBl[2];
#pragma unroll
    for (int b = 0; b < 2; ++b) {
        char* base = smem + b * 36864;
        sAh[b] = (_Float16*)base;
        sAl[b] = (_Float16*)(base + 8192);
        sBh[b] = (_Float16*)(base + 16384);
        sBl[b] = (_Float16*)(base + 26624);
    }
    float* Cred = (float*)smem;  // [64][160] epilogue union
    f32x4 acc[4][5] = {};
    float4 pre[5];
    auto loadB = [&](int kt) {
#pragma unroll
        for (int j = 0; j < 5; ++j) {
            const int c = tid + j * 256;
            pre[j] = *(const float4*)(seg + (brow0 + (c >> 3)) * 1024L + (kt << 5) +
                                      ((c & 7) << 2));
        }
    };
    auto writeB = [&](int buf) {
#pragma unroll
        for (int j = 0; j < 5; ++j) cvt_store(pre[j], tid + j * 256, sBh[buf], sBl[buf]);
    };
    loadB(0);
    dma_plane(AH, (long)bm * 128, 1024, 0, sAh[0], tid);
    dma_plane(AL, (long)bm * 128, 1024, 0, sAl[0], tid);
    writeB(0);
    loadB(1);
    __syncthreads();
    for (int kt = 0; kt < 32; ++kt) {
        const int cur = kt & 1, nxt = cur ^ 1;
        if (kt < 31) {
            const int kcol = (kt + 1) << 5;
            dma_plane(AH, (long)bm * 128, 1024, kcol, sAh[nxt], tid);
            dma_plane(AL, (long)bm * 128, 1024, kcol, sAl[nxt], tid);
            writeB(nxt);                      // consumes pre = B(kt+1)
            if (kt < 30) loadB(kt + 2);
        }
        f16x8 aH[4], aL[4];
#pragma unroll
        for (int tm = 0; tm < 4; ++tm) {
            const int row = wm * 64 + tm * 16 + l15;
            aH[tm] = *(const f16x8*)&sAh[cur][swz(row, q)];
            aL[tm] = *(const f16x8*)&sAl[cur][swz(row, q)];
        }
#pragma unroll
        for (int tn = 0; tn < 5; ++tn) {
            const int rowb = wn * 80 + tn * 16 + l15;
            const f16x8 bH = *(const f16x8*)&sBh[cur][swz(rowb, q)];
            const f16x8 bL = *(const f16x8*)&sBl[cur][swz(rowb, q)];
#pragma unroll
            for (int tm = 0; tm < 4; ++tm) {
                acc[tm][tn] = __builtin_amdgcn_mfma_f32_16x16x32_f16(aH[tm], bH, acc[tm][tn], 0, 0, 0);
                acc[tm][tn] = __builtin_amdgcn_mfma_f32_16x16x32_f16(aH[tm], bL, acc[tm][tn], 0, 0, 0);
                acc[tm][tn] = __builtin_amdgcn_mfma_f32_16x16x32_f16(aL[tm], bH, acc[tm][tn], 0, 0, 0);
            }
        }
        __syncthreads();
    }
    // epilogue: two 64-row chunks through LDS ([64][160]: hh*10 mod 32 distinct)
    for (int c = 0; c < 2; ++c) {
        __syncthreads();
        if (wm == c) {
#pragma unroll
            for (int tm = 0; tm < 4; ++tm)
#pragma unroll
                for (int tn = 0; tn < 5; ++tn)
#pragma unroll
                    for (int r = 0; r < 4; ++r)
                        Cred[(tm * 16 + q * 4 + r) * 160 + wn * 80 + tn * 16 + l15] =
                            acc[tm][tn][r];
        }
        __syncthreads();
        for (int p = tid; p < 1024; p += 256) {
            const int bb = p >> 4, hh = p & 15;
            const float* d = &Cred[bb * 160 + hh * 10];
            float best = d[0], ba = fabsf(d[0]);
#pragma unroll
            for (int s = 1; s < 10; ++s) {
                const float v = d[s], a = fabsf(v);
                if (a > ba) { ba = a; best = v; }  // strict >: first occurrence
            }
            const float gate = 1.f / (1.f + expf(-best));
            const int bg = bm * 128 + c * 64 + bb;
            const int h = bn * 16 + hh;
            gates[(long)bg * 2048 + h] = gate;
        }
    }
}

// ---------------------------------------------------------------------------
// KWinners: v = y*gate (fp32); exact 102nd-largest via radix select on
// order-preserving uint keys; keep where key >= kth (jnp tie semantics);
// emit h as f16 hi/lo planes.
// ---------------------------------------------------------------------------
__global__ __launch_bounds__(256) void kwinners_kernel(const float* __restrict__ y,
                                                       const float* __restrict__ g,
                                                       _Float16* __restrict__ hH,
                                                       _Float16* __restrict__ hL) {
    __shared__ unsigned hist[256];
    __shared__ unsigned scan[257];
    __shared__ int sb, srank;
    const int tid = threadIdx.x;
    const long base = (long)blockIdx.x * 2048;
    float v[8];
    unsigned u[8];
#pragma unroll
    for (int j = 0; j < 8; ++j) {
        const int i = j * 256 + tid;
        const float val = y[base + i] * g[base + i];
        v[j] = val;
        const unsigned b = __float_as_uint(val);
        u[j] = b ^ (unsigned)((((int)b) >> 31) | 0x80000000);  // monotone map
    }
    unsigned prefix = 0, pmask = 0;
    int rank = 102;
    for (int round = 0; round < 4; ++round) {
        const int shift = 24 - (round << 3);
        hist[tid] = 0;
        if (tid == 0) scan[256] = 0;
        __syncthreads();
#pragma unroll
        for (int j = 0; j < 8; ++j)
            if ((u[j] & pmask) == prefix) atomicAdd(&hist[(u[j] >> shift) & 255], 1u);
        __syncthreads();
        scan[tid] = hist[tid];
        __syncthreads();
        for (int off = 1; off < 256; off <<= 1) {  // inclusive suffix sum
            const unsigned t = scan[tid] + ((tid + off < 256) ? scan[tid + off] : 0u);
            __syncthreads();
            scan[tid] = t;
            __syncthreads();
        }
        if (scan[tid] >= (unsigned)rank && scan[tid + 1] < (unsigned)rank) {
            sb = tid;
            srank = rank - (int)scan[tid + 1];
        }
        __syncthreads();
        prefix |= ((unsigned)sb) << shift;
        pmask |= 255u << shift;
        rank = srank;
        __syncthreads();
    }
#pragma unroll
    for (int j = 0; j < 8; ++j) {
        const int i = j * 256 + tid;
        const float hv = (u[j] >= prefix) ? v[j] : 0.f;
        const _Float16 hi = (_Float16)hv;
        hH[base + i] = hi;
        hL[base + i] = (_Float16)(hv - (float)hi);
    }
}

// ---------------------------------------------------------------------------
extern "C" void kernel_launch(void* const* d_in, const int* in_sizes, int n_in,
                              void* d_out, int out_size, void* d_ws, size_t ws_size,
                              hipStream_t stream) {
    const float* x    = (const float*)d_in[0];
    const float* ctx  = (const float*)d_in[1];
    const float* w1   = (const float*)d_in[2];
    const float* b1   = (const float*)d_in[3];
    const float* seg1 = (const float*)d_in[4];
    const float* w2   = (const float*)d_in[5];
    const float* b2   = (const float*)d_in[6];
    const float* seg2 = (const float*)d_in[7];
    const float* wo   = (const float*)d_in[8];
    const float* bo   = (const float*)d_in[9];

    // 96 MB workspace, three 32 MB regions, time-multiplexed (round-3 layout).
    char* base = (char*)d_ws;
    float*    gates = (float*)base;
    char*     r1    = base + (32L << 20);
    _Float16* ctxH  = (_Float16*)r1;
    _Float16* ctxL  = (_Float16*)(r1 + (8L << 20));
    float*    yb    = (float*)r1;
    char*     r2    = base + (64L << 20);
    _Float16* xH    = (_Float16*)r2;
    _Float16* xL    = (_Float16*)(r2 + (8L << 20));
    _Float16* hH    = (_Float16*)r2;
    _Float16* hL    = (_Float16*)(r2 + (16L << 20));
    (void)ws_size;

    const int n4_ctx = (4096 * 1024) / 4;

    // layer 1
    split_kernel<<<dim3(4096), dim3(256), 0, stream>>>(ctx, ctxH, ctxL, n4_ctx);
    split_kernel<<<dim3(4096), dim3(256), 0, stream>>>(x, xH, xL, n4_ctx);
    dend_gemm<<<dim3(128, 32), dim3(256), 0, stream>>>(ctxH, ctxL, seg1, gates);
    gemm_split<<<dim3(16, 32), dim3(256), 0, stream>>>(xH, xL, w1, b1, yb, 2048, 1024);
    kwinners_kernel<<<dim3(4096), dim3(256), 0, stream>>>(yb, gates, hH, hL);
    // layer 2 (re-split ctx: its region was clobbered by y)
    split_kernel<<<dim3(4096), dim3(256), 0, stream>>>(ctx, ctxH, ctxL, n4_ctx);
    dend_gemm<<<dim3(128, 32), dim3(256), 0, stream>>>(ctxH, ctxL, seg2, gates);
    gemm_split<<<dim3(16, 32), dim3(256), 0, stream>>>(hH, hL, w2, b2, yb, 2048, 2048);
    kwinners_kernel<<<dim3(4096), dim3(256), 0, stream>>>(yb, gates, hH, hL);
    // output layer
    gemm_split<<<dim3(8, 32), dim3(256), 0, stream>>>(hH, hL, wo, bo, (float*)d_out,
                                                      1024, 2048);
}

// Round 5
// 1459.555 us; speedup vs baseline: 1.2180x; 1.2180x over previous
//
#include <hip/hip_runtime.h>

// ---------------------------------------------------------------------------
// DendriticMLP on MI355X — round 5.
// f16 hi/lo split GEMMs (3-term MFMA hh+hl+lh, ~2^-21 rel err) — decisions
// (abs-max gating, top-k) match fp32 reference. Round-4 dbuf regressed
// (m99/m132 pattern); reverted to the proven two-barrier K-loop and instead
// removed staging VALU: dendrite GEMM now DMAs BOTH operands from pre-split
// f16 planes (pure global_load_lds, m97 structure, 60 MFMA/barrier).
// Memory (96 MB proven budget): gates1[0,32) gates2[32,64) | ctx planes
// [64,80) | seg-eighth planes [80,90) reused 16x ||| then y[64,96),
// kwinners writes h planes IN PLACE over y (row-interleaved hi|lo, 8 KB/row),
// y2/h2 planes [0,32) after gates1 dies.
// ---------------------------------------------------------------------------

#define AS1 __attribute__((address_space(1)))
#define AS3 __attribute__((address_space(3)))

typedef _Float16 f16x8 __attribute__((ext_vector_type(8)));
typedef _Float16 f16x4 __attribute__((ext_vector_type(4)));
typedef float    f32x4 __attribute__((ext_vector_type(4)));

// swizzled halfword offset of logical chunk q (0..3) in row of a [rows][32]
// f16 tile: physical chunk = q ^ ((row>>1)&3) -> frag reads 2-way max (free).
__device__ __forceinline__ int swz(int row, int q) {
    return row * 32 + ((q ^ ((row >> 1) & 3)) << 3);
}

// ---------------------------------------------------------------------------
// split: fp32 -> f16 hi + f16 lo planes (a ~= hi+lo, err ~2^-22 |a|)
// ---------------------------------------------------------------------------
__global__ __launch_bounds__(256) void split_kernel(const float* __restrict__ s,
                                                    _Float16* __restrict__ hi,
                                                    _Float16* __restrict__ lo, int n4) {
    int i = blockIdx.x * 256 + threadIdx.x;
    if (i >= n4) return;
    float4 a = ((const float4*)s)[i];
    f16x4 h, l;
    h.x = (_Float16)a.x; l.x = (_Float16)(a.x - (float)h.x);
    h.y = (_Float16)a.y; l.y = (_Float16)(a.y - (float)h.y);
    h.z = (_Float16)a.z; l.z = (_Float16)(a.z - (float)h.z);
    h.w = (_Float16)a.w; l.w = (_Float16)(a.w - (float)h.w);
    ((f16x4*)hi)[i] = h;
    ((f16x4*)lo)[i] = l;
}

// DMA `chunks` 16B-chunks of a [rows][32]-halfword tile (plane ld = ldHalf,
// k-offset kcol) into swizzled LDS. Wave-uniform LDS base + lane*16 (HW rule).
__device__ __forceinline__ void dma_tile(const _Float16* __restrict__ g, long row0,
                                         int ldHalf, int kcol, _Float16* lds, int tid,
                                         int chunks) {
    for (int s = tid; s < chunks; s += 256) {
        const int row = s >> 2, cp = s & 3;
        const int src = cp ^ ((row >> 1) & 3);   // logical chunk at this slot
        const _Float16* gp = g + (row0 + row) * (long)ldHalf + kcol + src * 8;
        __builtin_amdgcn_global_load_lds((const AS1 void*)gp,
                                         (AS3 void*)(lds + ((s & ~63) << 3)), 16, 0, 0);
    }
}

// convert a prefetched float4 to hi/lo f16x4 and store to swizzled LDS planes
__device__ __forceinline__ void cvt_store(const float4 v, int c, _Float16* sH,
                                          _Float16* sL) {
    const int row = c >> 3, hc = c & 7;
    f16x4 h, l;
    h.x = (_Float16)v.x; l.x = (_Float16)(v.x - (float)h.x);
    h.y = (_Float16)v.y; l.y = (_Float16)(v.y - (float)h.y);
    h.z = (_Float16)v.z; l.z = (_Float16)(v.z - (float)h.z);
    h.w = (_Float16)v.w; l.w = (_Float16)(v.w - (float)h.w);
    const int off = row * 32 + (((hc >> 1) ^ ((row >> 1) & 3)) << 3) + ((hc & 1) << 2);
    *(f16x4*)(sH + off) = h;
    *(f16x4*)(sL + off) = l;
}

// ---------------------------------------------------------------------------
// Dendrite GEMM, pure-DMA both operands + abs-max gating epilogue.
// dend[b,n] = ctx[b,:].seg[n,:], n local to a 2560-row (256 h-unit) eighth.
// Tile 128(b) x 160(n) = 16 h-groups x 10 segments. Two-barrier K-loop,
// 60 MFMA per barrier, zero staging VALU.
// Epilogue: acc -> LDS [64][160], argmax_s |dend| (strict > = jnp.argmax),
// gates[b][qoff + h] = sigmoid(selected), fp32.
// ---------------------------------------------------------------------------
__global__ __launch_bounds__(256) void dend_gemm(const _Float16* __restrict__ AH,
                                                 const _Float16* __restrict__ AL,
                                                 const _Float16* __restrict__ BH,
                                                 const _Float16* __restrict__ BL,
                                                 float* __restrict__ gates, int qoff) {
    __shared__ __align__(16) char smem[40960];
    _Float16* sAh = (_Float16*)smem;            //  8192 B (128x32)
    _Float16* sAl = (_Float16*)(smem + 8192);   //  8192 B
    _Float16* sBh = (_Float16*)(smem + 16384);  // 10240 B (160x32)
    _Float16* sBl = (_Float16*)(smem + 26624);  // 10240 B
    float* Cred = (float*)smem;                 // [64][160] epilogue union
    const int tid = threadIdx.x;
    const int w = tid >> 6, lane = tid & 63;
    const int wm = w >> 1, wn = w & 1;
    const int q = lane >> 4, l15 = lane & 15;
    const int bm = blockIdx.y, bn = blockIdx.x;
    const long arow0 = (long)bm * 128, brow0 = (long)bn * 160;
    f32x4 acc[4][5] = {};
    for (int kt = 0; kt < 32; ++kt) {
        __syncthreads();  // previous iteration's frag reads complete
        const int kcol = kt << 5;
        dma_tile(AH, arow0, 1024, kcol, sAh, tid, 512);
        dma_tile(AL, arow0, 1024, kcol, sAl, tid, 512);
        dma_tile(BH, brow0, 1024, kcol, sBh, tid, 640);
        dma_tile(BL, brow0, 1024, kcol, sBl, tid, 640);
        __syncthreads();  // vmcnt(0): DMA landed (covered by co-resident blocks)
        f16x8 aH[4], aL[4];
#pragma unroll
        for (int tm = 0; tm < 4; ++tm) {
            const int row = wm * 64 + tm * 16 + l15;
            aH[tm] = *(const f16x8*)&sAh[swz(row, q)];
            aL[tm] = *(const f16x8*)&sAl[swz(row, q)];
        }
#pragma unroll
        for (int tn = 0; tn < 5; ++tn) {
            const int rowb = wn * 80 + tn * 16 + l15;
            const f16x8 bH = *(const f16x8*)&sBh[swz(rowb, q)];
            const f16x8 bL = *(const f16x8*)&sBl[swz(rowb, q)];
#pragma unroll
            for (int tm = 0; tm < 4; ++tm) {
                acc[tm][tn] = __builtin_amdgcn_mfma_f32_16x16x32_f16(aH[tm], bH, acc[tm][tn], 0, 0, 0);
                acc[tm][tn] = __builtin_amdgcn_mfma_f32_16x16x32_f16(aH[tm], bL, acc[tm][tn], 0, 0, 0);
                acc[tm][tn] = __builtin_amdgcn_mfma_f32_16x16x32_f16(aL[tm], bH, acc[tm][tn], 0, 0, 0);
            }
        }
    }
    // epilogue: two 64-row chunks through LDS ([64][160]: hh*10 mod 32 distinct)
    for (int c = 0; c < 2; ++c) {
        __syncthreads();
        if (wm == c) {
#pragma unroll
            for (int tm = 0; tm < 4; ++tm)
#pragma unroll
                for (int tn = 0; tn < 5; ++tn)
#pragma unroll
                    for (int r = 0; r < 4; ++r)
                        Cred[(tm * 16 + q * 4 + r) * 160 + wn * 80 + tn * 16 + l15] =
                            acc[tm][tn][r];
        }
        __syncthreads();
        for (int p = tid; p < 1024; p += 256) {
            const int bb = p >> 4, hh = p & 15;
            const float* d = &Cred[bb * 160 + hh * 10];
            float best = d[0], ba = fabsf(d[0]);
#pragma unroll
            for (int s = 1; s < 10; ++s) {
                const float v = d[s], a = fabsf(v);
                if (a > ba) { ba = a; best = v; }  // strict >: first occurrence
            }
            const float gate = 1.f / (1.f + expf(-best));
            const int bg = bm * 128 + c * 64 + bb;
            gates[(long)bg * 2048 + qoff + bn * 16 + hh] = gate;
        }
    }
}

// ---------------------------------------------------------------------------
// GEMM variant 1 (layer-2/out): A = f16 hi/lo planes DMA'd with row stride
// ldA halfwords (supports kwinners' row-interleaved hi|lo layout, ldA=4096);
// B fp32 (register prefetch + in-kernel split). Round-3 two-barrier K-loop.
// C[M,N] = A @ B[N,K]^T + bias.
// ---------------------------------------------------------------------------
__global__ __launch_bounds__(256) void gemm_adma(
    const _Float16* __restrict__ AH, const _Float16* __restrict__ AL, int ldA,
    const float* __restrict__ B, const float* __restrict__ bias,
    float* __restrict__ C, int N, int K) {
    __shared__ __align__(16) _Float16 sAh[4096], sAl[4096], sBh[4096], sBl[4096];
    const int tid = threadIdx.x;
    const int w = tid >> 6, lane = tid & 63;
    const int wm = w >> 1, wn = w & 1;
    const int q = lane >> 4, l15 = lane & 15;
    const int bm = blockIdx.y, bn = blockIdx.x;
    const long arow0 = (long)bm * 128, brow0 = (long)bn * 128;
    f32x4 acc[4][4] = {};
    float4 pre[4];
    auto loadB = [&](int kt) {
#pragma unroll
        for (int j = 0; j < 4; ++j) {
            const int c = tid + j * 256;
            pre[j] = *(const float4*)(B + (brow0 + (c >> 3)) * (long)K + (kt << 5) +
                                      ((c & 7) << 2));
        }
    };
    loadB(0);
    const int ksteps = K >> 5;
    for (int kt = 0; kt < ksteps; ++kt) {
        __syncthreads();
        const int kcol = kt << 5;
        dma_tile(AH, arow0, ldA, kcol, sAh, tid, 512);
        dma_tile(AL, arow0, ldA, kcol, sAl, tid, 512);
#pragma unroll
        for (int j = 0; j < 4; ++j) cvt_store(pre[j], tid + j * 256, sBh, sBl);
        if (kt + 1 < ksteps) loadB(kt + 1);
        __syncthreads();
        f16x8 aH[4], aL[4];
#pragma unroll
        for (int tm = 0; tm < 4; ++tm) {
            const int row = wm * 64 + tm * 16 + l15;
            aH[tm] = *(const f16x8*)&sAh[swz(row, q)];
            aL[tm] = *(const f16x8*)&sAl[swz(row, q)];
        }
#pragma unroll
        for (int tn = 0; tn < 4; ++tn) {
            const int rowb = wn * 64 + tn * 16 + l15;
            const f16x8 bH = *(const f16x8*)&sBh[swz(rowb, q)];
            const f16x8 bL = *(const f16x8*)&sBl[swz(rowb, q)];
#pragma unroll
            for (int tm = 0; tm < 4; ++tm) {
                acc[tm][tn] = __builtin_amdgcn_mfma_f32_16x16x32_f16(aH[tm], bH, acc[tm][tn], 0, 0, 0);
                acc[tm][tn] = __builtin_amdgcn_mfma_f32_16x16x32_f16(aH[tm], bL, acc[tm][tn], 0, 0, 0);
                acc[tm][tn] = __builtin_amdgcn_mfma_f32_16x16x32_f16(aL[tm], bH, acc[tm][tn], 0, 0, 0);
            }
        }
    }
    float bv[4];
#pragma unroll
    for (int tn = 0; tn < 4; ++tn) bv[tn] = bias[bn * 128 + wn * 64 + tn * 16 + l15];
#pragma unroll
    for (int tm = 0; tm < 4; ++tm) {
        const int m0 = bm * 128 + wm * 64 + tm * 16 + q * 4;
#pragma unroll
        for (int tn = 0; tn < 4; ++tn) {
            const int n = bn * 128 + wn * 64 + tn * 16 + l15;
#pragma unroll
            for (int r = 0; r < 4; ++r)
                C[(long)(m0 + r) * N + n] = acc[tm][tn][r] + bv[tn];
        }
    }
}

// ---------------------------------------------------------------------------
// GEMM variant 2 (layer-1): both A and B fp32, register prefetch + in-kernel
// split (x is a raw input; no planes exist for it).
// ---------------------------------------------------------------------------
__global__ __launch_bounds__(256) void gemm_ab(
    const float* __restrict__ A, const float* __restrict__ B,
    const float* __restrict__ bias, float* __restrict__ C, int N, int K) {
    __shared__ __align__(16) _Float16 sAh[4096], sAl[4096], sBh[4096], sBl[4096];
    const int tid = threadIdx.x;
    const int w = tid >> 6, lane = tid & 63;
    const int wm = w >> 1, wn = w & 1;
    const int q = lane >> 4, l15 = lane & 15;
    const int bm = blockIdx.y, bn = blockIdx.x;
    const long arow0 = (long)bm * 128, brow0 = (long)bn * 128;
    f32x4 acc[4][4] = {};
    float4 preA[4], preB[4];
    auto loadAB = [&](int kt) {
#pragma unroll
        for (int j = 0; j < 4; ++j) {
            const int c = tid + j * 256;
            preA[j] = *(const float4*)(A + (arow0 + (c >> 3)) * (long)K + (kt << 5) +
                                       ((c & 7) << 2));
            preB[j] = *(const float4*)(B + (brow0 + (c >> 3)) * (long)K + (kt << 5) +
                                       ((c & 7) << 2));
        }
    };
    loadAB(0);
    const int ksteps = K >> 5;
    for (int kt = 0; kt < ksteps; ++kt) {
        __syncthreads();
#pragma unroll
        for (int j = 0; j < 4; ++j) {
            cvt_store(preA[j], tid + j * 256, sAh, sAl);
            cvt_store(preB[j], tid + j * 256, sBh, sBl);
        }
        if (kt + 1 < ksteps) loadAB(kt + 1);
        __syncthreads();
        f16x8 aH[4], aL[4];
#pragma unroll
        for (int tm = 0; tm < 4; ++tm) {
            const int row = wm * 64 + tm * 16 + l15;
            aH[tm] = *(const f16x8*)&sAh[swz(row, q)];
            aL[tm] = *(const f16x8*)&sAl[swz(row, q)];
        }
#pragma unroll
        for (int tn = 0; tn < 4; ++tn) {
            const int rowb = wn * 64 + tn * 16 + l15;
            const f16x8 bH = *(const f16x8*)&sBh[swz(rowb, q)];
            const f16x8 bL = *(const f16x8*)&sBl[swz(rowb, q)];
#pragma unroll
            for (int tm = 0; tm < 4; ++tm) {
                acc[tm][tn] = __builtin_amdgcn_mfma_f32_16x16x32_f16(aH[tm], bH, acc[tm][tn], 0, 0, 0);
                acc[tm][tn] = __builtin_amdgcn_mfma_f32_16x16x32_f16(aH[tm], bL, acc[tm][tn], 0, 0, 0);
                acc[tm][tn] = __builtin_amdgcn_mfma_f32_16x16x32_f16(aL[tm], bH, acc[tm][tn], 0, 0, 0);
            }
        }
    }
    float bv[4];
#pragma unroll
    for (int tn = 0; tn < 4; ++tn) bv[tn] = bias[bn * 128 + wn * 64 + tn * 16 + l15];
#pragma unroll
    for (int tm = 0; tm < 4; ++tm) {
        const int m0 = bm * 128 + wm * 64 + tm * 16 + q * 4;
#pragma unroll
        for (int tn = 0; tn < 4; ++tn) {
            const int n = bn * 128 + wn * 64 + tn * 16 + l15;
#pragma unroll
            for (int r = 0; r < 4; ++r)
                C[(long)(m0 + r) * N + n] = acc[tm][tn][r] + bv[tn];
        }
    }
}

// ---------------------------------------------------------------------------
// KWinners: v = y*gate (fp32); exact 102nd-largest via radix select on
// order-preserving uint keys; keep where key >= kth (jnp tie semantics).
// Writes h planes IN PLACE over y, row-interleaved: row b occupies the same
// 8 KB as y row b: halfwords [4096b,4096b+2048) = hi, [+2048,+4096) = lo.
// Safe: all reads of row b complete (barrier-ordered) before writes; one
// block owns exactly one row.
// ---------------------------------------------------------------------------
__global__ __launch_bounds__(256) void kwinners_kernel(float* __restrict__ y,
                                                       const float* __restrict__ g) {
    __shared__ unsigned hist[256];
    __shared__ unsigned scan[257];
    __shared__ int sb, srank;
    const int tid = threadIdx.x;
    const long base = (long)blockIdx.x * 2048;
    float v[8];
    unsigned u[8];
#pragma unroll
    for (int j = 0; j < 8; ++j) {
        const int i = j * 256 + tid;
        const float val = y[base + i] * g[base + i];
        v[j] = val;
        const unsigned b = __float_as_uint(val);
        u[j] = b ^ (unsigned)((((int)b) >> 31) | 0x80000000);  // monotone map
    }
    unsigned prefix = 0, pmask = 0;
    int rank = 102;
    for (int round = 0; round < 4; ++round) {
        const int shift = 24 - (round << 3);
        hist[tid] = 0;
        if (tid == 0) scan[256] = 0;
        __syncthreads();
#pragma unroll
        for (int j = 0; j < 8; ++j)
            if ((u[j] & pmask) == prefix) atomicAdd(&hist[(u[j] >> shift) & 255], 1u);
        __syncthreads();
        scan[tid] = hist[tid];
        __syncthreads();
        for (int off = 1; off < 256; off <<= 1) {  // inclusive suffix sum
            const unsigned t = scan[tid] + ((tid + off < 256) ? scan[tid + off] : 0u);
            __syncthreads();
            scan[tid] = t;
            __syncthreads();
        }
        if (scan[tid] >= (unsigned)rank && scan[tid + 1] < (unsigned)rank) {
            sb = tid;
            srank = rank - (int)scan[tid + 1];
        }
        __syncthreads();
        prefix |= ((unsigned)sb) << shift;
        pmask |= 255u << shift;
        rank = srank;
        __syncthreads();
    }
    _Float16* hp = (_Float16*)y;
    const long hb = (long)blockIdx.x * 4096;
#pragma unroll
    for (int j = 0; j < 8; ++j) {
        const int i = j * 256 + tid;
        const float hv = (u[j] >= prefix) ? v[j] : 0.f;
        const _Float16 hi = (_Float16)hv;
        hp[hb + i] = hi;                              // hi plane (first 4 KB)
        hp[hb + 2048 + i] = (_Float16)(hv - (float)hi);  // lo plane (next 4 KB)
    }
}

// ---------------------------------------------------------------------------
extern "C" void kernel_launch(void* const* d_in, const int* in_sizes, int n_in,
                              void* d_out, int out_size, void* d_ws, size_t ws_size,
                              hipStream_t stream) {
    const float* x    = (const float*)d_in[0];
    const float* ctx  = (const float*)d_in[1];
    const float* w1   = (const float*)d_in[2];
    const float* b1   = (const float*)d_in[3];
    const float* seg1 = (const float*)d_in[4];
    const float* w2   = (const float*)d_in[5];
    const float* b2   = (const float*)d_in[6];
    const float* seg2 = (const float*)d_in[7];
    const float* wo   = (const float*)d_in[8];
    const float* bo   = (const float*)d_in[9];

    char* W = (char*)d_ws;  // 96 MB budget (proven safe in rounds 2-4)
    float*    gates1 = (float*)W;                     // [ 0,32) MB
    float*    gates2 = (float*)(W + (32L << 20));     // [32,64) MB
    _Float16* ctxH   = (_Float16*)(W + (64L << 20));  // [64,72) MB
    _Float16* ctxL   = (_Float16*)(W + (72L << 20));  // [72,80) MB
    _Float16* segH   = (_Float16*)(W + (80L << 20));  // [80,85) MB (eighth)
    _Float16* segL   = (_Float16*)(W + (85L << 20));  // [85,90) MB
    float*    yb     = (float*)(W + (64L << 20));     // [64,96) MB (after dends)
    float*    yb2    = (float*)W;                     // [ 0,32) MB (after kw1)
    (void)ws_size;

    // --- dendrite gates for both layers (only need ctx + seg) ---
    split_kernel<<<dim3(4096), dim3(256), 0, stream>>>(ctx, ctxH, ctxL,
                                                       (4096 * 1024) / 4);
    for (int l = 0; l < 2; ++l) {
        const float* seg = l ? seg2 : seg1;
        float* gates = l ? gates2 : gates1;
        for (int e = 0; e < 8; ++e) {  // 2560 seg-rows (256 h units) per eighth
            const float* sq = seg + (long)e * 2560 * 1024;
            split_kernel<<<dim3(2560), dim3(256), 0, stream>>>(sq, segH, segL,
                                                               (2560 * 1024) / 4);
            dend_gemm<<<dim3(16, 32), dim3(256), 0, stream>>>(ctxH, ctxL, segH, segL,
                                                              gates, e * 256);
        }
    }
    // --- layer 1 ---
    gemm_ab<<<dim3(16, 32), dim3(256), 0, stream>>>(x, w1, b1, yb, 2048, 1024);
    kwinners_kernel<<<dim3(4096), dim3(256), 0, stream>>>(yb, gates1);
    // --- layer 2 (A = h planes interleaved in yb, ldA = 4096 halfwords) ---
    gemm_adma<<<dim3(16, 32), dim3(256), 0, stream>>>(
        (const _Float16*)yb, (const _Float16*)yb + 2048, 4096, w2, b2, yb2, 2048, 2048);
    kwinners_kernel<<<dim3(4096), dim3(256), 0, stream>>>(yb2, gates2);
    // --- output layer ---
    gemm_adma<<<dim3(8, 32), dim3(256), 0, stream>>>(
        (const _Float16*)yb2, (const _Float16*)yb2 + 2048, 4096, wo, bo,
        (float*)d_out, 1024, 2048);
}